// Round 10
// baseline (156.864 us; speedup 1.0000x reference)
//
#include <hip/hip_runtime.h>
#include <hip/hip_fp16.h>

// LBP semantic dependency, channel-difference form, base-2 domain.
//   d'(x,p) = sp(x+p) - sp(x);  db[a,u] = edge + sum_{v!=a,u} sum_t d'-terms
// All db quantities in units of ln2. tp = e^p quantized fp16.
// R18 = 2-SLICE PIPELINED BLOCK (grid 160, one round):
//   R17 accounting: issue ~16us of 64 (VALUBusy 25%) -> 75% stall = serialized
//   {stage(mem, ~12us chip-wide burst) -> sweeps(issue)} x 2 rounds with a
//   192-idle-CU tail. 2 blocks/CU impossible (slab set 155KB). Fix: block
//   owns BOTH n-slices of its a. Slice-0 staged to LDS; slice-1 pre-loaded
//   and half-packed into 42 regs/thread during the same memory phase; after
//   slice-0's pipeline, regs -> slab (cheap ds_writes, no HBM wait) and the
//   slice-1 pipeline runs. One round, one memory phase, same total traffic.
// + d2 pair-log2: log2(nm0*nm1)-log2(dn0*dn1); nm<=2^62 -> pair <=2^124 safe
//   (d3 pairs would reach 2^214 at clamp 45 -> left unpaired).

#define S    160
#define S2   25600            // 160*160
#define S3   4096000          // 160^3 (per-n slab, elements)
#define STR  162              // LDS slab row stride in halves (bank-spread pad)
#define C2E  1.4426950408889634f

__device__ __forceinline__ float fexp2(float x) { return __builtin_amdgcn_exp2f(x); }
__device__ __forceinline__ float flog2(float x) { return __builtin_amdgcn_logf(x); }
__device__ __forceinline__ float cdb(float x) {
    return fminf(fmaxf(x, -45.f), 45.f);  // saturated beyond ~30 either way;
}                                         // keeps folded/paired terms in fp32
__device__ __forceinline__ float sp2t(float tp) { return flog2(1.f + tp); }
__device__ __forceinline__ float Ff(float x, float tp) {
    float tx = fexp2(x);
    return flog2(1.f + tx * tp) - flog2(1.f + tx);
}
__device__ __forceinline__ const float* selT(int t, const float* a,
                                             const float* b, const float* c) {
    return (t == 0) ? a : (t == 1) ? b : c;
}

// One block per a (both n-slices). 960 threads (15 waves), 163,200B LDS,
// 1 block/CU; grid 160 <= 256 CUs -> single dispatch round.
__global__ __launch_bounds__(960)
void k_fused(const float* __restrict__ s_sib, const float* __restrict__ s_cop,
             const float* __restrict__ s_grd, const float* __restrict__ s_edge,
             float* __restrict__ outp)
{
    int a = blockIdx.x;                   // 0..159
    int tid = threadIdx.x;
    int u4 = tid % 40, r = tid / 40;      // staging map (r 0..23, v = r+24i)
    int us = tid % S,  vs = tid / S;      // sweep map   (vs 0..5, v = 6k+vs)

    __shared__ __half tp3[3 * S * STR];   // tp3[t][v][u]           (155,520 B)
    __shared__ float  scr[1280];          // ph1 / sweep partials     (5,120 B)
    __shared__ float  db1s[S], db2s[S], E1[S], E2[S];               // (2,560 B)

    // ---- phase 1a: stage slice n=0 into the slab; fp32 ph1 product-partials
    float4 acc0 = make_float4(0.f, 0.f, 0.f, 0.f);
    #pragma unroll
    for (int t = 0; t < 3; ++t) {
        const float* g = selT(t, s_sib, s_cop, s_grd) + (long)a * S + u4 * 4;
        float4 pv[7];
        #pragma unroll
        for (int i = 0; i < 6; ++i)
            pv[i] = *(const float4*)(g + (long)(r + 24 * i) * S2);
        if (r < 16) pv[6] = *(const float4*)(g + (long)(r + 144) * S2);
        float4 P = make_float4(1.f, 1.f, 1.f, 1.f);
        #pragma unroll
        for (int i = 0; i < 7; ++i) {
            if (i == 6 && r >= 16) break;
            int v = r + 24 * i;
            float t0 = fexp2(pv[i].x * C2E), t1 = fexp2(pv[i].y * C2E);
            float t2 = fexp2(pv[i].z * C2E), t3 = fexp2(pv[i].w * C2E);
            P.x = __builtin_fmaf(P.x, t0, P.x);
            P.y = __builtin_fmaf(P.y, t1, P.y);
            P.z = __builtin_fmaf(P.z, t2, P.z);
            P.w = __builtin_fmaf(P.w, t3, P.w);
            __half* b = &tp3[t * (S * STR) + v * STR + u4 * 4];
            *(__half2*)(b)     = __floats2half2_rn(t0, t1);
            *(__half2*)(b + 2) = __floats2half2_rn(t2, t3);
        }
        acc0.x += flog2(P.x); acc0.y += flog2(P.y);
        acc0.z += flog2(P.z); acc0.w += flog2(P.w);
    }
    // ---- phase 1b: slice n=1 -> 21 uint2 of packed halves in REGISTERS
    float4 acc1 = make_float4(0.f, 0.f, 0.f, 0.f);
    uint2 ha1[21];
    #pragma unroll
    for (int t = 0; t < 3; ++t) {
        const float* g = selT(t, s_sib, s_cop, s_grd) + S3 + (long)a * S + u4 * 4;
        float4 pv[7];
        #pragma unroll
        for (int i = 0; i < 6; ++i)
            pv[i] = *(const float4*)(g + (long)(r + 24 * i) * S2);
        if (r < 16) pv[6] = *(const float4*)(g + (long)(r + 144) * S2);
        float4 P = make_float4(1.f, 1.f, 1.f, 1.f);
        #pragma unroll
        for (int i = 0; i < 7; ++i) {
            if (i == 6 && r >= 16) break;
            float t0 = fexp2(pv[i].x * C2E), t1 = fexp2(pv[i].y * C2E);
            float t2 = fexp2(pv[i].z * C2E), t3 = fexp2(pv[i].w * C2E);
            P.x = __builtin_fmaf(P.x, t0, P.x);
            P.y = __builtin_fmaf(P.y, t1, P.y);
            P.z = __builtin_fmaf(P.z, t2, P.z);
            P.w = __builtin_fmaf(P.w, t3, P.w);
            __half2 h01 = __floats2half2_rn(t0, t1);
            __half2 h23 = __floats2half2_rn(t2, t3);
            ha1[t * 7 + i].x = *(unsigned*)&h01;
            ha1[t * 7 + i].y = *(unsigned*)&h23;
        }
        acc1.x += flog2(P.x); acc1.y += flog2(P.y);
        acc1.z += flog2(P.z); acc1.w += flog2(P.w);
    }
    float edg0 = 0.f, edg1 = 0.f;
    if (tid < S) {
        edg0 = s_edge[tid * S + a] * C2E;
        edg1 = s_edge[S2 + tid * S + a] * C2E;
    }

    // ---- per-slice pipeline (ns = 0: slab already staged; ns = 1: regs->slab)
    #pragma unroll 1
    for (int ns = 0; ns < 2; ++ns) {
        if (ns == 1) {
            #pragma unroll
            for (int t = 0; t < 3; ++t)
                #pragma unroll
                for (int i = 0; i < 7; ++i) {
                    if (i == 6 && r >= 16) break;
                    int v = r + 24 * i;
                    *(uint2*)(&tp3[t * (S * STR) + v * STR + u4 * 4]) = ha1[t * 7 + i];
                }
            __syncthreads();
        }
        float4 accC = ns ? acc1 : acc0;
        float  edgC = ns ? edg1 : edg0;
        // ph1 reduce: 24 r-groups -> 8 (3-stage RMW)
        float4* scr4 = (float4*)scr;
        if (r < 8) scr4[r * 40 + u4] = accC;
        __syncthreads();
        if (r >= 8 && r < 16) {
            float4 o = scr4[(r - 8) * 40 + u4];
            o.x += accC.x; o.y += accC.y; o.z += accC.z; o.w += accC.w;
            scr4[(r - 8) * 40 + u4] = o;
        }
        __syncthreads();
        if (r >= 16) {
            float4 o = scr4[(r - 16) * 40 + u4];
            o.x += accC.x; o.y += accC.y; o.z += accC.z; o.w += accC.w;
            scr4[(r - 16) * 40 + u4] = o;
        }
        __syncthreads();
        // db1 + E1 (exclusion terms from the quantized slab)
        if (tid < S) {
            int u = tid, cu4 = u >> 2, cc = u & 3;
            float s = 0.f;
            #pragma unroll
            for (int g2 = 0; g2 < 8; ++g2) s += scr[(g2 * 40 + cu4) * 4 + cc];
            float rr = edgC + s - 480.f;
            #pragma unroll
            for (int t = 0; t < 3; ++t) {
                const __half* sl = &tp3[t * (S * STR)];
                float tpa = __half2float(sl[a * STR + u]);
                rr -= (sp2t(tpa) - 1.f);
                if (u != a) {
                    float tpu = __half2float(sl[u * STR + u]);
                    rr -= (sp2t(tpu) - 1.f);
                }
            }
            db1s[u] = rr;
            E1[u] = fexp2(cdb(rr) + 1.f);
        }
        __syncthreads();

        // d2 sweep, folded + PAIRED log2
        float d2acc = 0.f;
        #pragma unroll
        for (int t = 0; t < 3; ++t) {
            const __half* sl = &tp3[t * (S * STR)];
            for (int kb = 0; kb < 6; ++kb) {
                float tA[4], tB[4], Ev[4], nm[4], dn[4];
                #pragma unroll
                for (int j = 0; j < 4; ++j) {
                    int v = (kb * 4 + j) * 6 + vs;
                    tA[j] = __half2float(sl[v * STR + us]);
                    tB[j] = __half2float(sl[us * STR + v]);
                    Ev[j] = E1[v];
                }
                #pragma unroll
                for (int j = 0; j < 4; ++j) {
                    float B1 = 1.f + tB[j];
                    nm[j] = __builtin_fmaf(Ev[j], tA[j], B1);
                    dn[j] = B1 + Ev[j];
                }
                d2acc += flog2(nm[0] * nm[1]) - flog2(dn[0] * dn[1]);
                d2acc += flog2(nm[2] * nm[3]) - flog2(dn[2] * dn[3]);
            }
            #pragma unroll
            for (int k = 24; k < 27; ++k) {
                int v = k * 6 + vs;
                if (v < S) {
                    float tA = __half2float(sl[v * STR + us]);
                    float tB = __half2float(sl[us * STR + v]);
                    float B1 = 1.f + tB;
                    float nm = __builtin_fmaf(E1[v], tA, B1);
                    float dn = B1 + E1[v];
                    d2acc += flog2(nm) - flog2(dn);
                }
            }
        }
        scr[vs * S + us] = d2acc;
        __syncthreads();
        // db2 (inline di2) + E2
        if (tid < S) {
            int u = tid;
            float sw = scr[u] + scr[S + u] + scr[2 * S + u] + scr[3 * S + u]
                     + scr[4 * S + u] + scr[5 * S + u];
            float db1a1 = cdb(db1s[a]) + 1.f;
            float db1u1 = cdb(db1s[u]) + 1.f;
            float sum = 0.f;
            #pragma unroll
            for (int t = 0; t < 3; ++t) {
                const __half* sl = &tp3[t * (S * STR)];
                float tpa  = __half2float(sl[a * STR + u]);
                float tpba = __half2float(sl[u * STR + a]);
                sum += Ff(db1a1 - sp2t(tpba), tpa);           // C2(v=a)
                if (u != a) {
                    float tpu = __half2float(sl[u * STR + u]);
                    sum += Ff(db1u1 - sp2t(tpu), tpu);        // C2(v=u)
                }
            }
            float d2v = edgC - sum + sw;
            db2s[u] = d2v;
            E2[u] = fexp2(cdb(d2v));
        }
        __syncthreads();

        // d3 sweep, folded (unpaired: pair product could hit 2^214)
        float d3acc = 0.f;
        float E1u = E1[us];
        #pragma unroll
        for (int t = 0; t < 3; ++t) {
            const __half* sl = &tp3[t * (S * STR)];
            for (int kb = 0; kb < 6; ++kb) {
                float tA[4], tB[4], Ev[4];
                #pragma unroll
                for (int j = 0; j < 4; ++j) {
                    int v = (kb * 4 + j) * 6 + vs;
                    tA[j] = __half2float(sl[v * STR + us]);
                    tB[j] = __half2float(sl[us * STR + v]);
                    Ev[j] = E2[v];
                }
                #pragma unroll
                for (int j = 0; j < 4; ++j) {
                    float A1 = 1.f + tA[j];
                    float q  = A1 + E1u;
                    float rr = __builtin_fmaf(E1u, tB[j], A1);
                    float p  = Ev[j] * q;
                    float nm = __builtin_fmaf(p, tA[j], rr);
                    float dn = rr + p;
                    d3acc += flog2(nm) - flog2(dn);
                }
            }
            #pragma unroll
            for (int k = 24; k < 27; ++k) {
                int v = k * 6 + vs;
                if (v < S) {
                    float tA = __half2float(sl[v * STR + us]);
                    float tB = __half2float(sl[us * STR + v]);
                    float A1 = 1.f + tA;
                    float q  = A1 + E1u;
                    float rr = __builtin_fmaf(E1u, tB, A1);
                    float p  = E2[v] * q;
                    float nm = __builtin_fmaf(p, tA, rr);
                    float dn = rr + p;
                    d3acc += flog2(nm) - flog2(dn);
                }
            }
        }
        scr[vs * S + us] = d3acc;
        __syncthreads();
        // di3 + output (reads slab -> keep slab intact until after this)
        if (tid < S) {
            int u = tid;
            float sw = scr[u] + scr[S + u] + scr[2 * S + u] + scr[3 * S + u]
                     + scr[4 * S + u] + scr[5 * S + u];
            float db1u1 = cdb(db1s[u]) + 1.f;
            float db2a = cdb(db2s[a]);
            float db2u = cdb(db2s[u]);
            float sum = 0.f;
            #pragma unroll
            for (int t = 0; t < 3; ++t) {
                const __half* sl = &tp3[t * (S * STR)];
                float tpa  = __half2float(sl[a * STR + u]);
                float tpba = __half2float(sl[u * STR + a]);
                float d2vu = Ff(db1u1 - sp2t(tpa), tpba);
                sum += Ff(db2a - d2vu, tpa);                  // C3(v=a)
                if (u != a) {
                    float tpu = __half2float(sl[u * STR + u]);
                    float d2  = Ff(db1u1 - sp2t(tpu), tpu);
                    sum += Ff(db2u - d2, tpu);                // C3(v=u)
                }
            }
            float s = edgC - sum + sw;
            float sc  = fminf(fmaxf(s, -60.f), 60.f);
            float tsg = fexp2(-sc);
            float rr  = __fdividef(1.f, 1.f + tsg);
            long ob = ((long)(ns * S + u) * S + a) * 2;
            *(float2*)(outp + ob) = make_float2(tsg * rr, rr);
        }
        if (ns == 0) __syncthreads();   // di3 reads slab; protect before overwrite
    }
}

extern "C" void kernel_launch(void* const* d_in, const int* in_sizes, int n_in,
                              void* d_out, int out_size, void* d_ws, size_t ws_size,
                              hipStream_t stream) {
    const float* s_edge = (const float*)d_in[0];
    const float* s_sib  = (const float*)d_in[1];
    const float* s_cop  = (const float*)d_in[2];
    const float* s_grd  = (const float*)d_in[3];
    float* outp = (float*)d_out;
    (void)d_ws; (void)ws_size;          // workspace unused (no poison fills)

    k_fused<<<160, 960, 0, stream>>>(s_sib, s_cop, s_grd, s_edge, outp);
}